// Round 4
// baseline (1564.244 us; speedup 1.0000x reference)
//
#include <hip/hip_runtime.h>
#include <math.h>

#define DIM   1024
#define HID   2048
#define NEXP  8
#define MTOK  16384      // 4*4096 tokens
#define NSLOT 32768      // MTOK * top2

// header layout (ints) at ws+0
#define H_COUNT 0        // counts[8]
#define H_OFFS  8        // offsets[9]
#define H_CUR   24       // cursors[8]
#define H_NWORK 32       // n_work
#define H_WL    64       // worklist[<=263], (e<<16)|tile

typedef unsigned short ushort_t;
typedef unsigned int u32;
typedef __bf16 bf16x8 __attribute__((ext_vector_type(8)));
typedef float floatx4 __attribute__((ext_vector_type(4)));

__device__ __forceinline__ unsigned short f2bf(float f) {
  union { float f; unsigned int i; } z; z.f = f;
  unsigned int r = z.i + 0x7fffu + ((z.i >> 16) & 1u);
  return (unsigned short)(r >> 16);
}

// async global->LDS, 16B per lane. lds dest must be the wave-uniform base;
// HW scatters lane i to base + i*16.
__device__ __forceinline__ void gld16(const ushort_t* g, ushort_t* l) {
  __builtin_amdgcn_global_load_lds(
      (const __attribute__((address_space(1))) u32*)g,
      (__attribute__((address_space(3))) u32*)l, 16, 0, 0);
}

__global__ void k0_init(int* hdr) {
  int t = threadIdx.x;
  if (t < 64) hdr[t] = 0;
}

// fp32 -> bf16 conversion (grid-stride over float4s)
__global__ __launch_bounds__(256) void kconv(
    const float* __restrict__ src, ushort_t* __restrict__ dst, int n4)
{
  int i = blockIdx.x * 256 + threadIdx.x;
  int stride = gridDim.x * 256;
  for (; i < n4; i += stride) {
    float4 v = ((const float4*)src)[i];
    ushort4 o; o.x = f2bf(v.x); o.y = f2bf(v.y); o.z = f2bf(v.z); o.w = f2bf(v.w);
    ((ushort4*)dst)[i] = o;
  }
}

// RMSNorm + router + top2 + softmax. One block (256 thr)/token.
// Router reduction: LDS transpose-reduce (8 writes + 8 reads + 5 shuffle
// levels) instead of 8x6-level fp64 butterflies (~96 bpermutes/thread).
__global__ __launch_bounds__(256) void k1_norm_router(
    const float* __restrict__ x, const float* __restrict__ scale,
    const float* __restrict__ wr, ushort_t* __restrict__ xn,
    int* __restrict__ ids, float* __restrict__ wts, int* __restrict__ hdr)
{
  int token = blockIdx.x, t = threadIdx.x;
  int lane = t & 63, wid = t >> 6;

  float4 xv = ((const float4*)(x + (size_t)token * DIM))[t];
  double ss = (double)xv.x*xv.x + (double)xv.y*xv.y
            + (double)xv.z*xv.z + (double)xv.w*xv.w;
  #pragma unroll
  for (int o = 32; o; o >>= 1) ss += __shfl_down(ss, o, 64);

  __shared__ double sred[4];
  __shared__ float sbc;
  if (lane == 0) sred[wid] = ss;
  __syncthreads();
  if (t == 0) {
    double ms = (sred[0] + sred[1] + sred[2] + sred[3]) * (1.0 / (double)DIM);
    sbc = (float)(1.0 / sqrt(ms + 1e-6));
  }
  __syncthreads();
  float s = sbc;
  float4 sv = ((const float4*)scale)[t];
  float n0f = xv.x * s * sv.x, n1f = xv.y * s * sv.y;
  float n2f = xv.z * s * sv.z, n3f = xv.w * s * sv.w;
  ushort4 xo; xo.x = f2bf(n0f); xo.y = f2bf(n1f); xo.z = f2bf(n2f); xo.w = f2bf(n3f);
  ((ushort4*)(xn + (size_t)token * DIM))[t] = xo;

  // router scores from fp32 xn, fp64 accumulation
  double p[NEXP];
  #pragma unroll
  for (int e = 0; e < NEXP; e++) {
    float4 wv = ((const float4*)(wr + e * DIM))[t];
    p[e] = (double)n0f * wv.x + (double)n1f * wv.y
         + (double)n2f * wv.z + (double)n3f * wv.w;
  }
  // transpose-reduce: pl[e][t] -> 8 groups of 32 threads, one per expert
  __shared__ double pl[NEXP][256];
  #pragma unroll
  for (int e = 0; e < NEXP; e++) pl[e][t] = p[e];
  __syncthreads();
  int ge = t >> 5, gi = t & 31;                 // expert, index-in-group
  double v = 0.0;
  #pragma unroll
  for (int j = 0; j < 8; j++) v += pl[ge][gi + 32 * j];
  #pragma unroll
  for (int o = 16; o; o >>= 1) v += __shfl_xor(v, o, 64);  // within 32-group (32-aligned)
  __shared__ double scs[NEXP];
  if (gi == 0) scs[ge] = v;
  __syncthreads();
  if (t == 0) {
    double sc[NEXP];
    #pragma unroll
    for (int e = 0; e < NEXP; e++) sc[e] = scs[e];
    int e0 = 0;
    for (int e = 1; e < NEXP; e++) if (sc[e] > sc[e0]) e0 = e;        // ties: lowest idx
    int e1 = (e0 == 0) ? 1 : 0;
    for (int e = 0; e < NEXP; e++) if (e != e0 && sc[e] > sc[e1]) e1 = e;
    double d = exp(sc[e1] - sc[e0]);                                  // <= 1
    float w0 = (float)(1.0 / (1.0 + d));
    float w1 = (float)(d / (1.0 + d));
    ids[2 * token] = e0; ids[2 * token + 1] = e1;
    wts[2 * token] = w0; wts[2 * token + 1] = w1;
    atomicAdd(&hdr[H_COUNT + e0], 1);
    atomicAdd(&hdr[H_COUNT + e1], 1);
  }
}

// serial scan + worklist (tiny, deterministic work)
__global__ void k2_scan(int* hdr) {
  if (threadIdx.x == 0 && blockIdx.x == 0) {
    int off = 0;
    for (int e = 0; e < NEXP; e++) { hdr[H_OFFS + e] = off; off += hdr[H_COUNT + e]; }
    hdr[H_OFFS + NEXP] = off;
    int n = 0;
    for (int e = 0; e < NEXP; e++) {
      int tiles = (hdr[H_COUNT + e] + 127) >> 7;
      for (int i = 0; i < tiles; i++) hdr[H_WL + n++] = (e << 16) | i;
    }
    hdr[H_NWORK] = n;
  }
}

__global__ __launch_bounds__(256) void k3_scatter(
    const int* __restrict__ ids, int* __restrict__ hdr, int* __restrict__ perm)
{
  int s = blockIdx.x * 256 + threadIdx.x;
  if (s < NSLOT) {
    int e = ids[s];
    int pos = atomicAdd(&hdr[H_CUR + e], 1);
    perm[hdr[H_OFFS + e] + pos] = s;
  }
}

// T4 counted-vmcnt pipelined K-step (static buffers, raw barriers):
//   issue 4 gld16 -> NXT               (vmcnt 4 -> 8)
//   s_waitcnt vmcnt(4)                 (CUR's DMA retired; prefetch stays in flight)
//   s_barrier                          (B1: all waves' CUR loads landed)
//   ds_read CUR fragments
//   s_waitcnt lgkmcnt(0) + sched_barrier(0)   (reads done; rule #18 fence)
//   s_barrier                          (B2: all waves done reading CUR -> safe to overwrite)
//   16 MFMA                            (register-only; overlaps next step's issue)
// Race-free: every wave passes lgkmcnt(0) before B2; next overwrite of CUR is
// issued only after B2. Barriers uniform (kb, nrows uniform per block).
#define PIPE_STEP(CURA, CURB, NXTA, NXTB, DO_PREFETCH, WAITSTR)               \
  do {                                                                        \
    if (DO_PREFETCH) {                                                        \
      gld16(ap0, NXTA + woff); gld16(ap1, NXTA + woff + 512);                 \
      gld16(bp0, NXTB + woff); gld16(bp1, NXTB + woff + 512);                 \
      ap0 += 32; ap1 += 32; bp0 += 32; bp1 += 32;                             \
    }                                                                         \
    asm volatile("s_waitcnt " WAITSTR ::: "memory");                          \
    __builtin_amdgcn_s_barrier();                                             \
    bf16x8 af[4], bf[4];                                                      \
    _Pragma("unroll")                                                         \
    for (int ar = 0; ar < 4; ++ar) af[ar] = *(const bf16x8*)(CURA + abase + ar * 512); \
    _Pragma("unroll")                                                         \
    for (int bc = 0; bc < 4; ++bc) bf[bc] = *(const bf16x8*)(CURB + bbase + bc * 512); \
    asm volatile("s_waitcnt lgkmcnt(0)" ::: "memory");                        \
    __builtin_amdgcn_sched_barrier(0);                                        \
    __builtin_amdgcn_s_barrier();                                             \
    _Pragma("unroll")                                                         \
    for (int ar = 0; ar < 4; ++ar)                                            \
      _Pragma("unroll")                                                       \
      for (int bc = 0; bc < 4; ++bc)                                          \
        acc[ar][bc] = __builtin_amdgcn_mfma_f32_16x16x32_bf16(af[ar], bf[bc], acc[ar][bc], 0, 0, 0); \
  } while (0)

// grouped GEMM: up + SwiGLU. Tile 128 rows x 128 h-cols (64 u + 64 gate), K=1024.
// 2x2 waves x 64x64 each (4x4 16x16x32 frags). Counted-vmcnt double-buffer.
// B LDS col interleave: [0,32)=u, [32,64)=gate, [64,96)=u+32, [96,128)=gate+32
// so each wave's 64 cols hold matching u/gate halves (SwiGLU stays lane-local).
__global__ __launch_bounds__(256) void k4_up(
    const ushort_t* __restrict__ xn, const ushort_t* __restrict__ wup,
    const int* __restrict__ hdr, const int* __restrict__ perm,
    ushort_t* __restrict__ h)
{
  if ((int)blockIdx.y >= hdr[H_NWORK]) return;
  int wl = hdr[H_WL + blockIdx.y];
  int e = wl >> 16, tile = wl & 0xffff;
  int gs = hdr[H_OFFS + e];
  int row0 = gs + (tile << 7);
  int nrows = hdr[H_OFFS + e + 1] - row0; if (nrows > 128) nrows = 128;
  int n0 = blockIdx.x << 6;   // u-col base (0..2047 step 64)

  __shared__ __align__(16) ushort_t As[2][4096];  // dbuf [128 rows][32 k]
  __shared__ __align__(16) ushort_t Bs[2][4096];  // dbuf [128 cols][32 k]
  __shared__ int rowslot[128];

  int t = threadIdx.x;
  if (t < 128) rowslot[t] = (t < nrows) ? perm[row0 + t] : -1;

  int lane = t & 63, w = t >> 6;
  int wr = w >> 1, wc = w & 1;
  int r4 = lane >> 2, seg = lane & 3;

  // staging: wave w covers A rows [w*32, w*32+32) and B LDS cols [w*32, w*32+32)
  int rowA0 = w * 32 + r4;            // A issue 0
  int rowA1 = rowA0 + 16;             // A issue 1
  int tok0 = perm[row0 + (rowA0 < nrows ? rowA0 : 0)] >> 1;
  int tok1 = perm[row0 + (rowA1 < nrows ? rowA1 : 0)] >> 1;
  const ushort_t* ap0 = xn + (size_t)tok0 * DIM + seg * 8;
  const ushort_t* ap1 = xn + (size_t)tok1 * DIM + seg * 8;
  // B LDS col c = w*32 + j : global row = (w&1)*2048 + n0 + (w>>1)*32 + j
  const ushort_t* wbase = wup + (size_t)e * 4096 * DIM;
  const ushort_t* bp0 = wbase + (size_t)((w & 1) * 2048 + n0 + (w >> 1) * 32 + r4) * DIM + seg * 8;
  const ushort_t* bp1 = bp0 + (size_t)16 * DIM;

  int woff = w * 1024;
  ushort_t* As0 = &As[0][0]; ushort_t* As1 = &As[1][0];
  ushort_t* Bs0 = &Bs[0][0]; ushort_t* Bs1 = &Bs[1][0];

  floatx4 acc[4][4];
  #pragma unroll
  for (int i = 0; i < 4; i++)
    #pragma unroll
    for (int j = 0; j < 4; j++) acc[i][j] = (floatx4){0.f, 0.f, 0.f, 0.f};

  int quad = lane >> 4, l15 = lane & 15;
  int abase = ((wr * 64 + l15) << 5) + (quad << 3);
  int bbase = ((wc * 64 + l15) << 5) + (quad << 3);

  // prologue: stage K-block 0 into buffer 0
  gld16(ap0, As0 + woff); gld16(ap1, As0 + woff + 512);
  gld16(bp0, Bs0 + woff); gld16(bp1, Bs0 + woff + 512);
  ap0 += 32; ap1 += 32; bp0 += 32; bp1 += 32;

  const int NT = DIM / 32;  // 32, even
  for (int kb = 0; kb < NT - 2; kb += 2) {
    PIPE_STEP(As0, Bs0, As1, Bs1, true, "vmcnt(4)");
    PIPE_STEP(As1, Bs1, As0, Bs0, true, "vmcnt(4)");
  }
  PIPE_STEP(As0, Bs0, As1, Bs1, true, "vmcnt(4)");   // stages final K-block
  PIPE_STEP(As1, Bs1, As0, Bs0, false, "vmcnt(0)");  // final compute

  // SwiGLU: acc[ar][0..1] = u, acc[ar][2..3] = matching gate
  #pragma unroll
  for (int ar = 0; ar < 4; ++ar)
  #pragma unroll
  for (int p = 0; p < 2; ++p) {
    floatx4 u = acc[ar][p];
    floatx4 g = acc[ar][p + 2];
    #pragma unroll
    for (int j = 0; j < 4; ++j) {
      int r = wr * 64 + ar * 16 + quad * 4 + j;
      int slot = rowslot[r];
      if (slot >= 0) {
        float gv = g[j];
        float hv = u[j] * (gv / (1.0f + expf(-gv)));
        h[(size_t)slot * HID + n0 + wc * 32 + p * 16 + l15] = f2bf(hv);
      }
    }
  }
}

// grouped GEMM: down, weighted by softmax weight -> bf16 dwn. K=2048.
// Same 2x2-wave 64x64 decomposition + counted-vmcnt double-buffer.
__global__ __launch_bounds__(256) void k5_down(
    const ushort_t* __restrict__ h, const ushort_t* __restrict__ wdn,
    const int* __restrict__ hdr, const int* __restrict__ perm,
    const float* __restrict__ wts, ushort_t* __restrict__ dwn)
{
  if ((int)blockIdx.y >= hdr[H_NWORK]) return;
  int wl = hdr[H_WL + blockIdx.y];
  int e = wl >> 16, tile = wl & 0xffff;
  int gs = hdr[H_OFFS + e];
  int row0 = gs + (tile << 7);
  int nrows = hdr[H_OFFS + e + 1] - row0; if (nrows > 128) nrows = 128;
  int n0 = blockIdx.x << 7;   // out-col base (0..1023 step 128)

  __shared__ __align__(16) ushort_t As[2][4096];
  __shared__ __align__(16) ushort_t Bs[2][4096];
  __shared__ int rowslot[128];
  __shared__ float roww[128];

  int t = threadIdx.x;
  if (t < 128) {
    int sl = (t < nrows) ? perm[row0 + t] : -1;
    rowslot[t] = sl;
    roww[t] = (sl >= 0) ? wts[sl] : 0.f;
  }

  int lane = t & 63, w = t >> 6;
  int wr = w >> 1, wc = w & 1;
  int r4 = lane >> 2, seg = lane & 3;

  int rowA0 = w * 32 + r4;
  int rowA1 = rowA0 + 16;
  int sl0 = perm[row0 + (rowA0 < nrows ? rowA0 : 0)];
  int sl1 = perm[row0 + (rowA1 < nrows ? rowA1 : 0)];
  const ushort_t* ap0 = h + (size_t)sl0 * HID + seg * 8;
  const ushort_t* ap1 = h + (size_t)sl1 * HID + seg * 8;
  const ushort_t* wbase = wdn + (size_t)e * DIM * HID;
  const ushort_t* bp0 = wbase + (size_t)(n0 + w * 32 + r4) * HID + seg * 8;
  const ushort_t* bp1 = bp0 + (size_t)16 * HID;

  int woff = w * 1024;
  ushort_t* As0 = &As[0][0]; ushort_t* As1 = &As[1][0];
  ushort_t* Bs0 = &Bs[0][0]; ushort_t* Bs1 = &Bs[1][0];

  floatx4 acc[4][4];
  #pragma unroll
  for (int i = 0; i < 4; i++)
    #pragma unroll
    for (int j = 0; j < 4; j++) acc[i][j] = (floatx4){0.f, 0.f, 0.f, 0.f};

  int quad = lane >> 4, l15 = lane & 15;
  int abase = ((wr * 64 + l15) << 5) + (quad << 3);
  int bbase = ((wc * 64 + l15) << 5) + (quad << 3);

  // prologue: stage K-block 0 into buffer 0
  gld16(ap0, As0 + woff); gld16(ap1, As0 + woff + 512);
  gld16(bp0, Bs0 + woff); gld16(bp1, Bs0 + woff + 512);
  ap0 += 32; ap1 += 32; bp0 += 32; bp1 += 32;

  const int NT = HID / 32;  // 64, even
  for (int kb = 0; kb < NT - 2; kb += 2) {
    PIPE_STEP(As0, Bs0, As1, Bs1, true, "vmcnt(4)");
    PIPE_STEP(As1, Bs1, As0, Bs0, true, "vmcnt(4)");
  }
  PIPE_STEP(As0, Bs0, As1, Bs1, true, "vmcnt(4)");
  PIPE_STEP(As1, Bs1, As0, Bs0, false, "vmcnt(0)");

  #pragma unroll
  for (int ar = 0; ar < 4; ++ar)
  #pragma unroll
  for (int bc = 0; bc < 4; ++bc) {
    floatx4 d = acc[ar][bc];
    #pragma unroll
    for (int j = 0; j < 4; ++j) {
      int r = wr * 64 + ar * 16 + quad * 4 + j;
      int slot = rowslot[r];
      if (slot >= 0)
        dwn[(size_t)slot * DIM + n0 + wc * 64 + bc * 16 + l15] = f2bf(d[j] * roww[r]);
    }
  }
}

// out = x + dwn[2t] + dwn[2t+1]  (fp32 out, bf16 dwn)
__global__ __launch_bounds__(256) void k6_combine(
    const float* __restrict__ x, const ushort_t* __restrict__ dwn,
    float* __restrict__ out)
{
  int token = blockIdx.x, t = threadIdx.x;
  float4 xa = ((const float4*)(x + (size_t)token * DIM))[t];
  ushort4 a = ((const ushort4*)(dwn + (size_t)(2 * token)     * DIM))[t];
  ushort4 b = ((const ushort4*)(dwn + (size_t)(2 * token + 1) * DIM))[t];
  union { unsigned int i; float f; } c0, c1, c2, c3, d0, d1, d2, d3;
  c0.i = (u32)a.x << 16; c1.i = (u32)a.y << 16; c2.i = (u32)a.z << 16; c3.i = (u32)a.w << 16;
  d0.i = (u32)b.x << 16; d1.i = (u32)b.y << 16; d2.i = (u32)b.z << 16; d3.i = (u32)b.w << 16;
  float4 o;
  o.x = xa.x + c0.f + d0.f;
  o.y = xa.y + c1.f + d1.f;
  o.z = xa.z + c2.f + d2.f;
  o.w = xa.w + c3.f + d3.f;
  ((float4*)(out + (size_t)token * DIM))[t] = o;
}

extern "C" void kernel_launch(void* const* d_in, const int* in_sizes, int n_in,
                              void* d_out, int out_size, void* d_ws, size_t ws_size,
                              hipStream_t stream)
{
  const float* x   = (const float*)d_in[0];
  const float* sc  = (const float*)d_in[1];
  const float* wr  = (const float*)d_in[2];
  const float* wup = (const float*)d_in[3];
  const float* wdn = (const float*)d_in[4];
  float* out = (float*)d_out;

  char* ws = (char*)d_ws;
  int*      hdr  = (int*)ws;                          // 16 KB
  int*      ids  = (int*)(ws + 16384);                // [NSLOT]
  float*    wts  = (float*)(ws + 147456);             // [NSLOT]
  int*      perm = (int*)(ws + 278528);               // [NSLOT]
  ushort_t* xn   = (ushort_t*)(ws + 409600);          // 32 MB  [dead after k4]
  ushort_t* wupb = (ushort_t*)(ws + 33964032ull);     // 64 MB  [dead after k4]
  ushort_t* h    = (ushort_t*)(ws + 101072896ull);    // 128 MB
  ushort_t* wdnb = (ushort_t*)(ws + 67518464ull);     // 32 MB, upper half of wupb region
  ushort_t* dwn  = (ushort_t*)(ws + 409600);          // 64 MB, overlays xn + lower wupb
  // peak ws: 101072896 + 128MB = 235,290,624 B (~224 MiB)

  k0_init<<<1, 64, 0, stream>>>(hdr);
  kconv<<<4096, 256, 0, stream>>>(wup, wupb, NEXP * 2 * HID * DIM / 4);
  k1_norm_router<<<MTOK, 256, 0, stream>>>(x, sc, wr, xn, ids, wts, hdr);
  k2_scan<<<1, 64, 0, stream>>>(hdr);
  k3_scatter<<<NSLOT / 256, 256, 0, stream>>>(ids, hdr, perm);
  k4_up<<<dim3(32, 263), 256, 0, stream>>>(xn, wupb, hdr, perm, h);
  kconv<<<4096, 256, 0, stream>>>(wdn, wdnb, NEXP * DIM * HID / 4);
  k5_down<<<dim3(8, 263), 256, 0, stream>>>(h, wdnb, hdr, perm, wts, dwn);
  k6_combine<<<MTOK, 256, 0, stream>>>(x, dwn, out);
}

// Round 5
// 1283.313 us; speedup vs baseline: 1.2189x; 1.2189x over previous
//
#include <hip/hip_runtime.h>
#include <math.h>

#define DIM   1024
#define HID   2048
#define NEXP  8
#define MTOK  16384      // 4*4096 tokens
#define NSLOT 32768      // MTOK * top2

// header layout (ints) at ws+0
#define H_COUNT 0        // counts[8]
#define H_OFFS  8        // offsets[9]
#define H_CUR   24       // cursors[8]
#define H_NWORK 32       // n_work
#define H_WL    64       // worklist[<=263], (e<<16)|tile

typedef unsigned short ushort_t;
typedef unsigned int u32;
typedef __bf16 bf16x8 __attribute__((ext_vector_type(8)));
typedef float floatx4 __attribute__((ext_vector_type(4)));

__device__ __forceinline__ unsigned short f2bf(float f) {
  union { float f; unsigned int i; } z; z.f = f;
  unsigned int r = z.i + 0x7fffu + ((z.i >> 16) & 1u);
  return (unsigned short)(r >> 16);
}

// async global->LDS, 16B per lane. lds dest must be the wave-uniform base;
// HW scatters lane i to base + i*16.
__device__ __forceinline__ void gld16(const ushort_t* g, ushort_t* l) {
  __builtin_amdgcn_global_load_lds(
      (const __attribute__((address_space(1))) u32*)g,
      (__attribute__((address_space(3))) u32*)l, 16, 0, 0);
}

__global__ void k0_init(int* hdr) {
  int t = threadIdx.x;
  if (t < 64) hdr[t] = 0;
}

// fp32 -> bf16 conversion (grid-stride over float4s)
__global__ __launch_bounds__(256) void kconv(
    const float* __restrict__ src, ushort_t* __restrict__ dst, int n4)
{
  int i = blockIdx.x * 256 + threadIdx.x;
  int stride = gridDim.x * 256;
  for (; i < n4; i += stride) {
    float4 v = ((const float4*)src)[i];
    ushort4 o; o.x = f2bf(v.x); o.y = f2bf(v.y); o.z = f2bf(v.z); o.w = f2bf(v.w);
    ((ushort4*)dst)[i] = o;
  }
}

// RMSNorm + router + top2 + softmax. One block (256 thr)/token.
// Router reduction: LDS transpose-reduce (kept from R4; theory-sound, low risk).
__global__ __launch_bounds__(256) void k1_norm_router(
    const float* __restrict__ x, const float* __restrict__ scale,
    const float* __restrict__ wr, ushort_t* __restrict__ xn,
    int* __restrict__ ids, float* __restrict__ wts, int* __restrict__ hdr)
{
  int token = blockIdx.x, t = threadIdx.x;
  int lane = t & 63, wid = t >> 6;

  float4 xv = ((const float4*)(x + (size_t)token * DIM))[t];
  double ss = (double)xv.x*xv.x + (double)xv.y*xv.y
            + (double)xv.z*xv.z + (double)xv.w*xv.w;
  #pragma unroll
  for (int o = 32; o; o >>= 1) ss += __shfl_down(ss, o, 64);

  __shared__ double sred[4];
  __shared__ float sbc;
  if (lane == 0) sred[wid] = ss;
  __syncthreads();
  if (t == 0) {
    double ms = (sred[0] + sred[1] + sred[2] + sred[3]) * (1.0 / (double)DIM);
    sbc = (float)(1.0 / sqrt(ms + 1e-6));
  }
  __syncthreads();
  float s = sbc;
  float4 sv = ((const float4*)scale)[t];
  float n0f = xv.x * s * sv.x, n1f = xv.y * s * sv.y;
  float n2f = xv.z * s * sv.z, n3f = xv.w * s * sv.w;
  ushort4 xo; xo.x = f2bf(n0f); xo.y = f2bf(n1f); xo.z = f2bf(n2f); xo.w = f2bf(n3f);
  ((ushort4*)(xn + (size_t)token * DIM))[t] = xo;

  // router scores from fp32 xn, fp64 accumulation
  double p[NEXP];
  #pragma unroll
  for (int e = 0; e < NEXP; e++) {
    float4 wv = ((const float4*)(wr + e * DIM))[t];
    p[e] = (double)n0f * wv.x + (double)n1f * wv.y
         + (double)n2f * wv.z + (double)n3f * wv.w;
  }
  // transpose-reduce: pl[e][t] -> 8 groups of 32 threads, one per expert
  __shared__ double pl[NEXP][256];
  #pragma unroll
  for (int e = 0; e < NEXP; e++) pl[e][t] = p[e];
  __syncthreads();
  int ge = t >> 5, gi = t & 31;                 // expert, index-in-group
  double v = 0.0;
  #pragma unroll
  for (int j = 0; j < 8; j++) v += pl[ge][gi + 32 * j];
  #pragma unroll
  for (int o = 16; o; o >>= 1) v += __shfl_xor(v, o, 64);  // stays in 32-group
  __shared__ double scs[NEXP];
  if (gi == 0) scs[ge] = v;
  __syncthreads();
  if (t == 0) {
    double sc[NEXP];
    #pragma unroll
    for (int e = 0; e < NEXP; e++) sc[e] = scs[e];
    int e0 = 0;
    for (int e = 1; e < NEXP; e++) if (sc[e] > sc[e0]) e0 = e;        // ties: lowest idx
    int e1 = (e0 == 0) ? 1 : 0;
    for (int e = 0; e < NEXP; e++) if (e != e0 && sc[e] > sc[e1]) e1 = e;
    double d = exp(sc[e1] - sc[e0]);                                  // <= 1
    float w0 = (float)(1.0 / (1.0 + d));
    float w1 = (float)(d / (1.0 + d));
    ids[2 * token] = e0; ids[2 * token + 1] = e1;
    wts[2 * token] = w0; wts[2 * token + 1] = w1;
    atomicAdd(&hdr[H_COUNT + e0], 1);
    atomicAdd(&hdr[H_COUNT + e1], 1);
  }
}

// serial scan + worklist (tiny, deterministic work)
__global__ void k2_scan(int* hdr) {
  if (threadIdx.x == 0 && blockIdx.x == 0) {
    int off = 0;
    for (int e = 0; e < NEXP; e++) { hdr[H_OFFS + e] = off; off += hdr[H_COUNT + e]; }
    hdr[H_OFFS + NEXP] = off;
    int n = 0;
    for (int e = 0; e < NEXP; e++) {
      int tiles = (hdr[H_COUNT + e] + 127) >> 7;
      for (int i = 0; i < tiles; i++) hdr[H_WL + n++] = (e << 16) | i;
    }
    hdr[H_NWORK] = n;
  }
}

// block-aggregated scatter: LDS histogram + 1 global atomic per expert per
// block (1024 total vs 32768 contended; 8 counters x 4096-way was a suspected
// ~100us serialization). perm order within an expert changes -- harmless.
__global__ __launch_bounds__(256) void k3_scatter(
    const int* __restrict__ ids, int* __restrict__ hdr, int* __restrict__ perm)
{
  __shared__ int lcnt[NEXP];
  __shared__ int lbase[NEXP];
  int t = threadIdx.x;
  if (t < NEXP) lcnt[t] = 0;
  __syncthreads();
  int s = blockIdx.x * 256 + t;          // grid exact: NSLOT/256 blocks
  int e = ids[s];
  int lpos = atomicAdd(&lcnt[e], 1);     // LDS atomic
  __syncthreads();
  if (t < NEXP) lbase[t] = atomicAdd(&hdr[H_CUR + t], lcnt[t]);
  __syncthreads();
  perm[hdr[H_OFFS + e] + lbase[e] + lpos] = s;
}

// grouped GEMM: up + SwiGLU. Tile 128 rows x 128 h-cols (64 u + 64 gate), K=1024.
// R2-proven structure: 2x2 waves x 64x64 (4x4 frags), single-buffer LDS,
// 4 gld16 + 2 __syncthreads per K-step. x0 = colchunk offset (grid split in
// half purely so k5 + hidden kernels become visible in rocprof top-5).
// B LDS col interleave: [0,32)=u, [32,64)=gate, [64,96)=u+32, [96,128)=gate+32.
__global__ __launch_bounds__(256) void k4_up(
    const ushort_t* __restrict__ xn, const ushort_t* __restrict__ wup,
    const int* __restrict__ hdr, const int* __restrict__ perm,
    ushort_t* __restrict__ h, int x0)
{
  if ((int)blockIdx.y >= hdr[H_NWORK]) return;
  int wl = hdr[H_WL + blockIdx.y];
  int e = wl >> 16, tile = wl & 0xffff;
  int gs = hdr[H_OFFS + e];
  int row0 = gs + (tile << 7);
  int nrows = hdr[H_OFFS + e + 1] - row0; if (nrows > 128) nrows = 128;
  int n0 = (blockIdx.x + x0) << 6;   // u-col base (0..2047 step 64)

  __shared__ __align__(16) ushort_t As[4096];  // [128 rows][32 k]
  __shared__ __align__(16) ushort_t Bs[4096];  // [128 cols][32 k], u/gate interleaved
  __shared__ int rowslot[128];

  int t = threadIdx.x;
  if (t < 128) rowslot[t] = (t < nrows) ? perm[row0 + t] : -1;

  int lane = t & 63, w = t >> 6;
  int wr = w >> 1, wc = w & 1;
  int r4 = lane >> 2, seg = lane & 3;

  // staging: wave w covers A rows [w*32, w*32+32) and B LDS cols [w*32, w*32+32)
  int rowA0 = w * 32 + r4;            // A issue 0
  int rowA1 = rowA0 + 16;             // A issue 1
  int tok0 = perm[row0 + (rowA0 < nrows ? rowA0 : 0)] >> 1;
  int tok1 = perm[row0 + (rowA1 < nrows ? rowA1 : 0)] >> 1;
  const ushort_t* ap0 = xn + (size_t)tok0 * DIM + seg * 8;
  const ushort_t* ap1 = xn + (size_t)tok1 * DIM + seg * 8;
  // B LDS col c = w*32 + j : global row = (w&1)*2048 + n0 + (w>>1)*32 + j
  const ushort_t* wbase = wup + (size_t)e * 4096 * DIM;
  const ushort_t* bp0 = wbase + (size_t)((w & 1) * 2048 + n0 + (w >> 1) * 32 + r4) * DIM + seg * 8;
  const ushort_t* bp1 = bp0 + (size_t)16 * DIM;

  ushort_t* lA0 = As + w * 1024;
  ushort_t* lA1 = As + w * 1024 + 512;
  ushort_t* lB0 = Bs + w * 1024;
  ushort_t* lB1 = Bs + w * 1024 + 512;

  floatx4 acc[4][4];
  #pragma unroll
  for (int i = 0; i < 4; i++)
    #pragma unroll
    for (int j = 0; j < 4; j++) acc[i][j] = (floatx4){0.f, 0.f, 0.f, 0.f};

  int quad = lane >> 4, l15 = lane & 15;
  int abase = ((wr * 64 + l15) << 5) + (quad << 3);
  int bbase = ((wc * 64 + l15) << 5) + (quad << 3);

  for (int kb = 0; kb < DIM / 32; ++kb) {
    gld16(ap0, lA0); gld16(ap1, lA1); gld16(bp0, lB0); gld16(bp1, lB1);
    ap0 += 32; ap1 += 32; bp0 += 32; bp1 += 32;
    __syncthreads();   // drains vmcnt(0): DMA data visible to all
    bf16x8 af[4], bf[4];
    #pragma unroll
    for (int ar = 0; ar < 4; ++ar) af[ar] = *(const bf16x8*)(As + abase + ar * 512);
    #pragma unroll
    for (int bc = 0; bc < 4; ++bc) bf[bc] = *(const bf16x8*)(Bs + bbase + bc * 512);
    #pragma unroll
    for (int ar = 0; ar < 4; ++ar)
      #pragma unroll
      for (int bc = 0; bc < 4; ++bc)
        acc[ar][bc] = __builtin_amdgcn_mfma_f32_16x16x32_bf16(af[ar], bf[bc], acc[ar][bc], 0, 0, 0);
    __syncthreads();   // reads done before next iter's DMA overwrites
  }

  // SwiGLU: acc[ar][0..1] = u, acc[ar][2..3] = matching gate
  #pragma unroll
  for (int ar = 0; ar < 4; ++ar)
  #pragma unroll
  for (int p = 0; p < 2; ++p) {
    floatx4 u = acc[ar][p];
    floatx4 g = acc[ar][p + 2];
    #pragma unroll
    for (int j = 0; j < 4; ++j) {
      int r = wr * 64 + ar * 16 + quad * 4 + j;
      int slot = rowslot[r];
      if (slot >= 0) {
        float gv = g[j];
        float hv = u[j] * (gv / (1.0f + expf(-gv)));
        h[(size_t)slot * HID + n0 + wc * 32 + p * 16 + l15] = f2bf(hv);
      }
    }
  }
}

// grouped GEMM: down, weighted by softmax weight -> bf16 dwn. K=2048.
// R2-proven structure: 2x2-wave 64x64 decomposition. grid (8 colchunks, 263 tiles).
__global__ __launch_bounds__(256) void k5_down(
    const ushort_t* __restrict__ h, const ushort_t* __restrict__ wdn,
    const int* __restrict__ hdr, const int* __restrict__ perm,
    const float* __restrict__ wts, ushort_t* __restrict__ dwn)
{
  if ((int)blockIdx.y >= hdr[H_NWORK]) return;
  int wl = hdr[H_WL + blockIdx.y];
  int e = wl >> 16, tile = wl & 0xffff;
  int gs = hdr[H_OFFS + e];
  int row0 = gs + (tile << 7);
  int nrows = hdr[H_OFFS + e + 1] - row0; if (nrows > 128) nrows = 128;
  int n0 = blockIdx.x << 7;   // out-col base (0..1023 step 128)

  __shared__ __align__(16) ushort_t As[4096];  // [128 rows][32 k]
  __shared__ __align__(16) ushort_t Bs[4096];  // [128 cols][32 k]
  __shared__ int rowslot[128];
  __shared__ float roww[128];

  int t = threadIdx.x;
  if (t < 128) {
    int sl = (t < nrows) ? perm[row0 + t] : -1;
    rowslot[t] = sl;
    roww[t] = (sl >= 0) ? wts[sl] : 0.f;
  }

  int lane = t & 63, w = t >> 6;
  int wr = w >> 1, wc = w & 1;
  int r4 = lane >> 2, seg = lane & 3;

  int rowA0 = w * 32 + r4;
  int rowA1 = rowA0 + 16;
  int sl0 = perm[row0 + (rowA0 < nrows ? rowA0 : 0)];
  int sl1 = perm[row0 + (rowA1 < nrows ? rowA1 : 0)];
  const ushort_t* ap0 = h + (size_t)sl0 * HID + seg * 8;
  const ushort_t* ap1 = h + (size_t)sl1 * HID + seg * 8;
  const ushort_t* wbase = wdn + (size_t)e * DIM * HID;
  const ushort_t* bp0 = wbase + (size_t)(n0 + w * 32 + r4) * HID + seg * 8;
  const ushort_t* bp1 = bp0 + (size_t)16 * HID;

  ushort_t* lA0 = As + w * 1024;
  ushort_t* lA1 = As + w * 1024 + 512;
  ushort_t* lB0 = Bs + w * 1024;
  ushort_t* lB1 = Bs + w * 1024 + 512;

  floatx4 acc[4][4];
  #pragma unroll
  for (int i = 0; i < 4; i++)
    #pragma unroll
    for (int j = 0; j < 4; j++) acc[i][j] = (floatx4){0.f, 0.f, 0.f, 0.f};

  int quad = lane >> 4, l15 = lane & 15;
  int abase = ((wr * 64 + l15) << 5) + (quad << 3);
  int bbase = ((wc * 64 + l15) << 5) + (quad << 3);

  for (int kb = 0; kb < HID / 32; ++kb) {
    gld16(ap0, lA0); gld16(ap1, lA1); gld16(bp0, lB0); gld16(bp1, lB1);
    ap0 += 32; ap1 += 32; bp0 += 32; bp1 += 32;
    __syncthreads();
    bf16x8 af[4], bf[4];
    #pragma unroll
    for (int ar = 0; ar < 4; ++ar) af[ar] = *(const bf16x8*)(As + abase + ar * 512);
    #pragma unroll
    for (int bc = 0; bc < 4; ++bc) bf[bc] = *(const bf16x8*)(Bs + bbase + bc * 512);
    #pragma unroll
    for (int ar = 0; ar < 4; ++ar)
      #pragma unroll
      for (int bc = 0; bc < 4; ++bc)
        acc[ar][bc] = __builtin_amdgcn_mfma_f32_16x16x32_bf16(af[ar], bf[bc], acc[ar][bc], 0, 0, 0);
    __syncthreads();
  }

  #pragma unroll
  for (int ar = 0; ar < 4; ++ar)
  #pragma unroll
  for (int bc = 0; bc < 4; ++bc) {
    floatx4 d = acc[ar][bc];
    #pragma unroll
    for (int j = 0; j < 4; ++j) {
      int r = wr * 64 + ar * 16 + quad * 4 + j;
      int slot = rowslot[r];
      if (slot >= 0)
        dwn[(size_t)slot * DIM + n0 + wc * 64 + bc * 16 + l15] = f2bf(d[j] * roww[r]);
    }
  }
}

// out = x + dwn[2t] + dwn[2t+1]  (fp32 out, bf16 dwn)
__global__ __launch_bounds__(256) void k6_combine(
    const float* __restrict__ x, const ushort_t* __restrict__ dwn,
    float* __restrict__ out)
{
  int token = blockIdx.x, t = threadIdx.x;
  float4 xa = ((const float4*)(x + (size_t)token * DIM))[t];
  ushort4 a = ((const ushort4*)(dwn + (size_t)(2 * token)     * DIM))[t];
  ushort4 b = ((const ushort4*)(dwn + (size_t)(2 * token + 1) * DIM))[t];
  union { unsigned int i; float f; } c0, c1, c2, c3, d0, d1, d2, d3;
  c0.i = (u32)a.x << 16; c1.i = (u32)a.y << 16; c2.i = (u32)a.z << 16; c3.i = (u32)a.w << 16;
  d0.i = (u32)b.x << 16; d1.i = (u32)b.y << 16; d2.i = (u32)b.z << 16; d3.i = (u32)b.w << 16;
  float4 o;
  o.x = xa.x + c0.f + d0.f;
  o.y = xa.y + c1.f + d1.f;
  o.z = xa.z + c2.f + d2.f;
  o.w = xa.w + c3.f + d3.f;
  ((float4*)(out + (size_t)token * DIM))[t] = o;
}

extern "C" void kernel_launch(void* const* d_in, const int* in_sizes, int n_in,
                              void* d_out, int out_size, void* d_ws, size_t ws_size,
                              hipStream_t stream)
{
  const float* x   = (const float*)d_in[0];
  const float* sc  = (const float*)d_in[1];
  const float* wr  = (const float*)d_in[2];
  const float* wup = (const float*)d_in[3];
  const float* wdn = (const float*)d_in[4];
  float* out = (float*)d_out;

  char* ws = (char*)d_ws;
  int*      hdr  = (int*)ws;                          // 16 KB
  int*      ids  = (int*)(ws + 16384);                // [NSLOT]
  float*    wts  = (float*)(ws + 147456);             // [NSLOT]
  int*      perm = (int*)(ws + 278528);               // [NSLOT]
  ushort_t* xn   = (ushort_t*)(ws + 409600);          // 32 MB  [dead after k4]
  ushort_t* wupb = (ushort_t*)(ws + 33964032ull);     // 64 MB  [dead after k4]
  ushort_t* h    = (ushort_t*)(ws + 101072896ull);    // 128 MB
  ushort_t* wdnb = (ushort_t*)(ws + 67518464ull);     // 32 MB, upper half of wupb region
  ushort_t* dwn  = (ushort_t*)(ws + 409600);          // 64 MB, overlays xn + lower wupb
  // peak ws: 101072896 + 128MB = 235,290,624 B (~224 MiB)

  k0_init<<<1, 64, 0, stream>>>(hdr);
  kconv<<<4096, 256, 0, stream>>>(wup, wupb, NEXP * 2 * HID * DIM / 4);
  k1_norm_router<<<MTOK, 256, 0, stream>>>(x, sc, wr, xn, ids, wts, hdr);
  k2_scan<<<1, 64, 0, stream>>>(hdr);
  k3_scatter<<<NSLOT / 256, 256, 0, stream>>>(ids, hdr, perm);
  k4_up<<<dim3(16, 263), 256, 0, stream>>>(xn, wupb, hdr, perm, h, 0);   // cols 0..1023
  k4_up<<<dim3(16, 263), 256, 0, stream>>>(xn, wupb, hdr, perm, h, 16);  // cols 1024..2047
  kconv<<<4096, 256, 0, stream>>>(wdn, wdnb, NEXP * DIM * HID / 4);
  k5_down<<<dim3(8, 263), 256, 0, stream>>>(h, wdnb, hdr, perm, wts, dwn);
  k6_combine<<<MTOK, 256, 0, stream>>>(x, dwn, out);
}

// Round 6
// 951.408 us; speedup vs baseline: 1.6441x; 1.3489x over previous
//
#include <hip/hip_runtime.h>
#include <math.h>

#define DIM   1024
#define HID   2048
#define NEXP  8
#define MTOK  16384      // 4*4096 tokens
#define NSLOT 32768      // MTOK * top2

// header layout (ints) at ws+0
#define H_COUNT 0        // counts[8]
#define H_OFFS  8        // offsets[9]
#define H_CUR   24       // cursors[8]
#define H_NWORK 32       // n_work
#define H_WL    64       // worklist[<=263], (e<<16)|tile

typedef unsigned short ushort_t;
typedef unsigned int u32;
typedef __bf16 bf16x8 __attribute__((ext_vector_type(8)));
typedef float floatx4 __attribute__((ext_vector_type(4)));

__device__ __forceinline__ unsigned short f2bf(float f) {
  union { float f; unsigned int i; } z; z.f = f;
  unsigned int r = z.i + 0x7fffu + ((z.i >> 16) & 1u);
  return (unsigned short)(r >> 16);
}

// async global->LDS, 16B per lane. lds dest must be the wave-uniform base;
// HW scatters lane i to base + i*16.
__device__ __forceinline__ void gld16(const ushort_t* g, ushort_t* l) {
  __builtin_amdgcn_global_load_lds(
      (const __attribute__((address_space(1))) u32*)g,
      (__attribute__((address_space(3))) u32*)l, 16, 0, 0);
}

__global__ void k0_init(int* hdr) {
  int t = threadIdx.x;
  if (t < 64) hdr[t] = 0;
}

// fp32 -> bf16 conversion (grid-stride over float4s)
__global__ __launch_bounds__(256) void kconv(
    const float* __restrict__ src, ushort_t* __restrict__ dst, int n4)
{
  int i = blockIdx.x * 256 + threadIdx.x;
  int stride = gridDim.x * 256;
  for (; i < n4; i += stride) {
    float4 v = ((const float4*)src)[i];
    ushort4 o; o.x = f2bf(v.x); o.y = f2bf(v.y); o.z = f2bf(v.z); o.w = f2bf(v.w);
    ((ushort4*)dst)[i] = o;
  }
}

// RMSNorm + router + top2 + softmax. One block (256 thr)/token.
// NO per-token global atomics (R5 counters: 32768 same-cacheline atomics
// = ~190us of L2 serialization; counting moved to k1b_count).
__global__ __launch_bounds__(256) void k1_norm_router(
    const float* __restrict__ x, const float* __restrict__ scale,
    const float* __restrict__ wr, ushort_t* __restrict__ xn,
    int* __restrict__ ids, float* __restrict__ wts)
{
  int token = blockIdx.x, t = threadIdx.x;
  int lane = t & 63, wid = t >> 6;

  float4 xv = ((const float4*)(x + (size_t)token * DIM))[t];
  double ss = (double)xv.x*xv.x + (double)xv.y*xv.y
            + (double)xv.z*xv.z + (double)xv.w*xv.w;
  #pragma unroll
  for (int o = 32; o; o >>= 1) ss += __shfl_down(ss, o, 64);

  __shared__ double sred[4];
  __shared__ float sbc;
  if (lane == 0) sred[wid] = ss;
  __syncthreads();
  if (t == 0) {
    double ms = (sred[0] + sred[1] + sred[2] + sred[3]) * (1.0 / (double)DIM);
    sbc = (float)(1.0 / sqrt(ms + 1e-6));
  }
  __syncthreads();
  float s = sbc;
  float4 sv = ((const float4*)scale)[t];
  float n0f = xv.x * s * sv.x, n1f = xv.y * s * sv.y;
  float n2f = xv.z * s * sv.z, n3f = xv.w * s * sv.w;
  ushort4 xo; xo.x = f2bf(n0f); xo.y = f2bf(n1f); xo.z = f2bf(n2f); xo.w = f2bf(n3f);
  ((ushort4*)(xn + (size_t)token * DIM))[t] = xo;

  // router scores from fp32 xn, fp64 accumulation
  double p[NEXP];
  #pragma unroll
  for (int e = 0; e < NEXP; e++) {
    float4 wv = ((const float4*)(wr + e * DIM))[t];
    p[e] = (double)n0f * wv.x + (double)n1f * wv.y
         + (double)n2f * wv.z + (double)n3f * wv.w;
  }
  // transpose-reduce: pl[e][t] -> 8 groups of 32 threads, one per expert
  __shared__ double pl[NEXP][256];
  #pragma unroll
  for (int e = 0; e < NEXP; e++) pl[e][t] = p[e];
  __syncthreads();
  int ge = t >> 5, gi = t & 31;                 // expert, index-in-group
  double v = 0.0;
  #pragma unroll
  for (int j = 0; j < 8; j++) v += pl[ge][gi + 32 * j];
  #pragma unroll
  for (int o = 16; o; o >>= 1) v += __shfl_xor(v, o, 64);  // stays in 32-group
  __shared__ double scs[NEXP];
  if (gi == 0) scs[ge] = v;
  __syncthreads();
  if (t == 0) {
    double sc[NEXP];
    #pragma unroll
    for (int e = 0; e < NEXP; e++) sc[e] = scs[e];
    int e0 = 0;
    for (int e = 1; e < NEXP; e++) if (sc[e] > sc[e0]) e0 = e;        // ties: lowest idx
    int e1 = (e0 == 0) ? 1 : 0;
    for (int e = 0; e < NEXP; e++) if (e != e0 && sc[e] > sc[e1]) e1 = e;
    double d = exp(sc[e1] - sc[e0]);                                  // <= 1
    float w0 = (float)(1.0 / (1.0 + d));
    float w1 = (float)(d / (1.0 + d));
    ids[2 * token] = e0; ids[2 * token + 1] = e1;
    wts[2 * token] = w0; wts[2 * token + 1] = w1;
  }
}

// expert histogram: LDS-aggregated, 8 global atomics per block (512 total
// vs k1's old 32768 same-cacheline atomics).
__global__ __launch_bounds__(256) void k1b_count(
    const int* __restrict__ ids, int* __restrict__ hdr)
{
  __shared__ int lh[NEXP];
  int t = threadIdx.x;
  if (t < NEXP) lh[t] = 0;
  __syncthreads();
  int i = blockIdx.x * 256 + t;
  int stride = gridDim.x * 256;
  for (; i < NSLOT; i += stride) atomicAdd(&lh[ids[i]], 1);
  __syncthreads();
  if (t < NEXP && lh[t] > 0) atomicAdd(&hdr[H_COUNT + t], lh[t]);
}

// serial scan + worklist (tiny, deterministic work)
__global__ void k2_scan(int* hdr) {
  if (threadIdx.x == 0 && blockIdx.x == 0) {
    int off = 0;
    for (int e = 0; e < NEXP; e++) { hdr[H_OFFS + e] = off; off += hdr[H_COUNT + e]; }
    hdr[H_OFFS + NEXP] = off;
    int n = 0;
    for (int e = 0; e < NEXP; e++) {
      int tiles = (hdr[H_COUNT + e] + 127) >> 7;
      for (int i = 0; i < tiles; i++) hdr[H_WL + n++] = (e << 16) | i;
    }
    hdr[H_NWORK] = n;
  }
}

// block-aggregated scatter: LDS histogram + 1 global atomic per expert per
// block. perm order within an expert is nondeterministic -- harmless.
__global__ __launch_bounds__(256) void k3_scatter(
    const int* __restrict__ ids, int* __restrict__ hdr, int* __restrict__ perm)
{
  __shared__ int lcnt[NEXP];
  __shared__ int lbase[NEXP];
  int t = threadIdx.x;
  if (t < NEXP) lcnt[t] = 0;
  __syncthreads();
  int s = blockIdx.x * 256 + t;          // grid exact: NSLOT/256 blocks
  int e = ids[s];
  int lpos = atomicAdd(&lcnt[e], 1);     // LDS atomic
  __syncthreads();
  if (t < NEXP) lbase[t] = atomicAdd(&hdr[H_CUR + t], lcnt[t]);
  __syncthreads();
  perm[hdr[H_OFFS + e] + lbase[e] + lpos] = s;
}

// grouped GEMM: up + SwiGLU. Tile 128 rows x 128 h-cols (64 u + 64 gate), K=1024.
// R2-proven structure: 2x2 waves x 64x64 (4x4 frags), single-buffer LDS,
// 4 gld16 + 2 __syncthreads per K-step. x0 = colchunk offset (grid split in
// half so the slowest kernel stays visible in rocprof top-5).
// B LDS col interleave: [0,32)=u, [32,64)=gate, [64,96)=u+32, [96,128)=gate+32.
__global__ __launch_bounds__(256) void k4_up(
    const ushort_t* __restrict__ xn, const ushort_t* __restrict__ wup,
    const int* __restrict__ hdr, const int* __restrict__ perm,
    ushort_t* __restrict__ h, int x0)
{
  if ((int)blockIdx.y >= hdr[H_NWORK]) return;
  int wl = hdr[H_WL + blockIdx.y];
  int e = wl >> 16, tile = wl & 0xffff;
  int gs = hdr[H_OFFS + e];
  int row0 = gs + (tile << 7);
  int nrows = hdr[H_OFFS + e + 1] - row0; if (nrows > 128) nrows = 128;
  int n0 = (blockIdx.x + x0) << 6;   // u-col base (0..2047 step 64)

  __shared__ __align__(16) ushort_t As[4096];  // [128 rows][32 k]
  __shared__ __align__(16) ushort_t Bs[4096];  // [128 cols][32 k], u/gate interleaved
  __shared__ int rowslot[128];

  int t = threadIdx.x;
  if (t < 128) rowslot[t] = (t < nrows) ? perm[row0 + t] : -1;

  int lane = t & 63, w = t >> 6;
  int wr = w >> 1, wc = w & 1;
  int r4 = lane >> 2, seg = lane & 3;

  // staging: wave w covers A rows [w*32, w*32+32) and B LDS cols [w*32, w*32+32)
  int rowA0 = w * 32 + r4;            // A issue 0
  int rowA1 = rowA0 + 16;             // A issue 1
  int tok0 = perm[row0 + (rowA0 < nrows ? rowA0 : 0)] >> 1;
  int tok1 = perm[row0 + (rowA1 < nrows ? rowA1 : 0)] >> 1;
  const ushort_t* ap0 = xn + (size_t)tok0 * DIM + seg * 8;
  const ushort_t* ap1 = xn + (size_t)tok1 * DIM + seg * 8;
  // B LDS col c = w*32 + j : global row = (w&1)*2048 + n0 + (w>>1)*32 + j
  const ushort_t* wbase = wup + (size_t)e * 4096 * DIM;
  const ushort_t* bp0 = wbase + (size_t)((w & 1) * 2048 + n0 + (w >> 1) * 32 + r4) * DIM + seg * 8;
  const ushort_t* bp1 = bp0 + (size_t)16 * DIM;

  ushort_t* lA0 = As + w * 1024;
  ushort_t* lA1 = As + w * 1024 + 512;
  ushort_t* lB0 = Bs + w * 1024;
  ushort_t* lB1 = Bs + w * 1024 + 512;

  floatx4 acc[4][4];
  #pragma unroll
  for (int i = 0; i < 4; i++)
    #pragma unroll
    for (int j = 0; j < 4; j++) acc[i][j] = (floatx4){0.f, 0.f, 0.f, 0.f};

  int quad = lane >> 4, l15 = lane & 15;
  int abase = ((wr * 64 + l15) << 5) + (quad << 3);
  int bbase = ((wc * 64 + l15) << 5) + (quad << 3);

  for (int kb = 0; kb < DIM / 32; ++kb) {
    gld16(ap0, lA0); gld16(ap1, lA1); gld16(bp0, lB0); gld16(bp1, lB1);
    ap0 += 32; ap1 += 32; bp0 += 32; bp1 += 32;
    __syncthreads();   // drains vmcnt(0): DMA data visible to all
    bf16x8 af[4], bf[4];
    #pragma unroll
    for (int ar = 0; ar < 4; ++ar) af[ar] = *(const bf16x8*)(As + abase + ar * 512);
    #pragma unroll
    for (int bc = 0; bc < 4; ++bc) bf[bc] = *(const bf16x8*)(Bs + bbase + bc * 512);
    #pragma unroll
    for (int ar = 0; ar < 4; ++ar)
      #pragma unroll
      for (int bc = 0; bc < 4; ++bc)
        acc[ar][bc] = __builtin_amdgcn_mfma_f32_16x16x32_bf16(af[ar], bf[bc], acc[ar][bc], 0, 0, 0);
    __syncthreads();   // reads done before next iter's DMA overwrites
  }

  // SwiGLU: acc[ar][0..1] = u, acc[ar][2..3] = matching gate
  #pragma unroll
  for (int ar = 0; ar < 4; ++ar)
  #pragma unroll
  for (int p = 0; p < 2; ++p) {
    floatx4 u = acc[ar][p];
    floatx4 g = acc[ar][p + 2];
    #pragma unroll
    for (int j = 0; j < 4; ++j) {
      int r = wr * 64 + ar * 16 + quad * 4 + j;
      int slot = rowslot[r];
      if (slot >= 0) {
        float gv = g[j];
        float hv = u[j] * (gv / (1.0f + expf(-gv)));
        h[(size_t)slot * HID + n0 + wc * 32 + p * 16 + l15] = f2bf(hv);
      }
    }
  }
}

// grouped GEMM: down, weighted by softmax weight -> bf16 dwn. K=2048.
// R2-proven structure: 2x2-wave 64x64 decomposition. grid (8 colchunks, 263 tiles).
__global__ __launch_bounds__(256) void k5_down(
    const ushort_t* __restrict__ h, const ushort_t* __restrict__ wdn,
    const int* __restrict__ hdr, const int* __restrict__ perm,
    const float* __restrict__ wts, ushort_t* __restrict__ dwn)
{
  if ((int)blockIdx.y >= hdr[H_NWORK]) return;
  int wl = hdr[H_WL + blockIdx.y];
  int e = wl >> 16, tile = wl & 0xffff;
  int gs = hdr[H_OFFS + e];
  int row0 = gs + (tile << 7);
  int nrows = hdr[H_OFFS + e + 1] - row0; if (nrows > 128) nrows = 128;
  int n0 = blockIdx.x << 7;   // out-col base (0..1023 step 128)

  __shared__ __align__(16) ushort_t As[4096];  // [128 rows][32 k]
  __shared__ __align__(16) ushort_t Bs[4096];  // [128 cols][32 k]
  __shared__ int rowslot[128];
  __shared__ float roww[128];

  int t = threadIdx.x;
  if (t < 128) {
    int sl = (t < nrows) ? perm[row0 + t] : -1;
    rowslot[t] = sl;
    roww[t] = (sl >= 0) ? wts[sl] : 0.f;
  }

  int lane = t & 63, w = t >> 6;
  int wr = w >> 1, wc = w & 1;
  int r4 = lane >> 2, seg = lane & 3;

  int rowA0 = w * 32 + r4;
  int rowA1 = rowA0 + 16;
  int sl0 = perm[row0 + (rowA0 < nrows ? rowA0 : 0)];
  int sl1 = perm[row0 + (rowA1 < nrows ? rowA1 : 0)];
  const ushort_t* ap0 = h + (size_t)sl0 * HID + seg * 8;
  const ushort_t* ap1 = h + (size_t)sl1 * HID + seg * 8;
  const ushort_t* wbase = wdn + (size_t)e * DIM * HID;
  const ushort_t* bp0 = wbase + (size_t)(n0 + w * 32 + r4) * HID + seg * 8;
  const ushort_t* bp1 = bp0 + (size_t)16 * HID;

  ushort_t* lA0 = As + w * 1024;
  ushort_t* lA1 = As + w * 1024 + 512;
  ushort_t* lB0 = Bs + w * 1024;
  ushort_t* lB1 = Bs + w * 1024 + 512;

  floatx4 acc[4][4];
  #pragma unroll
  for (int i = 0; i < 4; i++)
    #pragma unroll
    for (int j = 0; j < 4; j++) acc[i][j] = (floatx4){0.f, 0.f, 0.f, 0.f};

  int quad = lane >> 4, l15 = lane & 15;
  int abase = ((wr * 64 + l15) << 5) + (quad << 3);
  int bbase = ((wc * 64 + l15) << 5) + (quad << 3);

  for (int kb = 0; kb < HID / 32; ++kb) {
    gld16(ap0, lA0); gld16(ap1, lA1); gld16(bp0, lB0); gld16(bp1, lB1);
    ap0 += 32; ap1 += 32; bp0 += 32; bp1 += 32;
    __syncthreads();
    bf16x8 af[4], bf[4];
    #pragma unroll
    for (int ar = 0; ar < 4; ++ar) af[ar] = *(const bf16x8*)(As + abase + ar * 512);
    #pragma unroll
    for (int bc = 0; bc < 4; ++bc) bf[bc] = *(const bf16x8*)(Bs + bbase + bc * 512);
    #pragma unroll
    for (int ar = 0; ar < 4; ++ar)
      #pragma unroll
      for (int bc = 0; bc < 4; ++bc)
        acc[ar][bc] = __builtin_amdgcn_mfma_f32_16x16x32_bf16(af[ar], bf[bc], acc[ar][bc], 0, 0, 0);
    __syncthreads();
  }

  #pragma unroll
  for (int ar = 0; ar < 4; ++ar)
  #pragma unroll
  for (int bc = 0; bc < 4; ++bc) {
    floatx4 d = acc[ar][bc];
    #pragma unroll
    for (int j = 0; j < 4; ++j) {
      int r = wr * 64 + ar * 16 + quad * 4 + j;
      int slot = rowslot[r];
      if (slot >= 0)
        dwn[(size_t)slot * DIM + n0 + wc * 64 + bc * 16 + l15] = f2bf(d[j] * roww[r]);
    }
  }
}

// out = x + dwn[2t] + dwn[2t+1]  (fp32 out, bf16 dwn)
__global__ __launch_bounds__(256) void k6_combine(
    const float* __restrict__ x, const ushort_t* __restrict__ dwn,
    float* __restrict__ out)
{
  int token = blockIdx.x, t = threadIdx.x;
  float4 xa = ((const float4*)(x + (size_t)token * DIM))[t];
  ushort4 a = ((const ushort4*)(dwn + (size_t)(2 * token)     * DIM))[t];
  ushort4 b = ((const ushort4*)(dwn + (size_t)(2 * token + 1) * DIM))[t];
  union { unsigned int i; float f; } c0, c1, c2, c3, d0, d1, d2, d3;
  c0.i = (u32)a.x << 16; c1.i = (u32)a.y << 16; c2.i = (u32)a.z << 16; c3.i = (u32)a.w << 16;
  d0.i = (u32)b.x << 16; d1.i = (u32)b.y << 16; d2.i = (u32)b.z << 16; d3.i = (u32)b.w << 16;
  float4 o;
  o.x = xa.x + c0.f + d0.f;
  o.y = xa.y + c1.f + d1.f;
  o.z = xa.z + c2.f + d2.f;
  o.w = xa.w + c3.f + d3.f;
  ((float4*)(out + (size_t)token * DIM))[t] = o;
}

extern "C" void kernel_launch(void* const* d_in, const int* in_sizes, int n_in,
                              void* d_out, int out_size, void* d_ws, size_t ws_size,
                              hipStream_t stream)
{
  const float* x   = (const float*)d_in[0];
  const float* sc  = (const float*)d_in[1];
  const float* wr  = (const float*)d_in[2];
  const float* wup = (const float*)d_in[3];
  const float* wdn = (const float*)d_in[4];
  float* out = (float*)d_out;

  char* ws = (char*)d_ws;
  int*      hdr  = (int*)ws;                          // 16 KB
  int*      ids  = (int*)(ws + 16384);                // [NSLOT]
  float*    wts  = (float*)(ws + 147456);             // [NSLOT]
  int*      perm = (int*)(ws + 278528);               // [NSLOT]
  ushort_t* xn   = (ushort_t*)(ws + 409600);          // 32 MB  [dead after k4]
  ushort_t* wupb = (ushort_t*)(ws + 33964032ull);     // 64 MB  [dead after k4]
  ushort_t* h    = (ushort_t*)(ws + 101072896ull);    // 128 MB
  ushort_t* wdnb = (ushort_t*)(ws + 67518464ull);     // 32 MB, upper half of wupb region
  ushort_t* dwn  = (ushort_t*)(ws + 409600);          // 64 MB, overlays xn + lower wupb
  // peak ws: 101072896 + 128MB = 235,290,624 B (~224 MiB)

  k0_init<<<1, 64, 0, stream>>>(hdr);
  kconv<<<4096, 256, 0, stream>>>(wup, wupb, NEXP * 2 * HID * DIM / 4);
  k1_norm_router<<<MTOK, 256, 0, stream>>>(x, sc, wr, xn, ids, wts);
  k1b_count<<<64, 256, 0, stream>>>(ids, hdr);
  k2_scan<<<1, 64, 0, stream>>>(hdr);
  k3_scatter<<<NSLOT / 256, 256, 0, stream>>>(ids, hdr, perm);
  k4_up<<<dim3(16, 263), 256, 0, stream>>>(xn, wupb, hdr, perm, h, 0);   // cols 0..1023
  k4_up<<<dim3(16, 263), 256, 0, stream>>>(xn, wupb, hdr, perm, h, 16);  // cols 1024..2047
  kconv<<<4096, 256, 0, stream>>>(wdn, wdnb, NEXP * DIM * HID / 4);
  k5_down<<<dim3(8, 263), 256, 0, stream>>>(h, wdnb, hdr, perm, wts, dwn);
  k6_combine<<<MTOK, 256, 0, stream>>>(x, dwn, out);
}